// Round 2
// baseline (107.021 us; speedup 1.0000x reference)
//
#include <hip/hip_runtime.h>
#include <hip/hip_bf16.h>

#define NEGINF -1000000000.0f

typedef __attribute__((ext_vector_type(4))) float f32x4;
typedef _Float16 half8 __attribute__((ext_vector_type(8)));
typedef _Float16 half4 __attribute__((ext_vector_type(4)));

constexpr int Bn = 64, Cn = 1024, Qn = 128, Dn = 128;

// ---------------- K0: precompute ----------------
// grid (9, Bn): bx<8 -> c_term for 128 ctx rows; bx==8 -> query prep for batch b.
__global__ __launch_bounds__(256) void k0_kernel(
    const float* __restrict__ ctx, const float* __restrict__ qry,
    const float* __restrict__ W, const float* __restrict__ mask,
    float* __restrict__ ct_g, float* __restrict__ qterm,
    _Float16* __restrict__ qh, _Float16* __restrict__ qT)
{
    __shared__ float wls[384];
    __shared__ _Float16 qs[128][132];
    const int b = blockIdx.y, bx = blockIdx.x, t = threadIdx.x;
    for (int i = t; i < 384; i += 256) wls[i] = W[i];
    __syncthreads();

    if (bx < 8) {
        int c = bx * 128 + (t >> 1), h = t & 1;
        const float* crow = ctx + ((size_t)b * Cn + c) * Dn + h * 64;
        float acc = 0.f;
        for (int j = 0; j < 64; j += 4) {
            f32x4 v = *(const f32x4*)(crow + j);
            int d = h * 64 + j;
            acc += v.x * wls[d] + v.y * wls[d + 1] + v.z * wls[d + 2] + v.w * wls[d + 3];
        }
        acc += __shfl_xor(acc, 1);
        if (h == 0) ct_g[(size_t)b * Cn + c] = acc;
    } else {
        const float* qB = qry + (size_t)b * Qn * Dn;
        // pass1: qh (fp16 row-major) + LDS stage
        for (int idx = t; idx < 128 * 32; idx += 256) {
            int q = idx >> 5, d4 = (idx & 31) * 4;
            f32x4 v = *(const f32x4*)(qB + q * Dn + d4);
            half4 hv;
            hv[0] = (_Float16)v.x; hv[1] = (_Float16)v.y;
            hv[2] = (_Float16)v.z; hv[3] = (_Float16)v.w;
            *(half4*)(qh + ((size_t)b * Qn + q) * Dn + d4) = hv;
            *(half4*)(&qs[q][d4]) = hv;
        }
        __syncthreads();
        // pass2: qT (fp16 transposed)
        for (int idx = t; idx < 128 * 32; idx += 256) {
            int d = idx >> 5, q4 = (idx & 31) * 4;
            half4 hv;
            hv[0] = qs[q4 + 0][d]; hv[1] = qs[q4 + 1][d];
            hv[2] = qs[q4 + 2][d]; hv[3] = qs[q4 + 3][d];
            *(half4*)(qT + ((size_t)b * Dn + d) * Qn + q4) = hv;
        }
        // pass3: qterm (+mask)
        int q = t >> 1, h = t & 1;
        const float* qrow = qB + q * Dn + h * 64;
        float acc = 0.f;
        for (int j = 0; j < 64; j += 4) {
            f32x4 v = *(const f32x4*)(qrow + j);
            int d = h * 64 + j;
            acc += v.x * wls[128 + d] + v.y * wls[128 + d + 1]
                 + v.z * wls[128 + d + 2] + v.w * wls[128 + d + 3];
        }
        acc += __shfl_xor(acc, 1);
        if (h == 0) qterm[(size_t)b * Qn + q] = acc + (1.0f - mask[b * Qn + q]) * NEGINF;
    }
}

// ---------------- K1: S^T, softmax over q, c2q; cols 1,2; ws_m ----------------
// grid (16, Bn): 64 ctx rows per block, 4 waves x 16 cols.
__global__ __launch_bounds__(256) void k1_kernel(
    const float* __restrict__ ctx, const _Float16* __restrict__ qh,
    const _Float16* __restrict__ qT, const float* __restrict__ W,
    const float* __restrict__ qterm, const float* __restrict__ ct_g,
    float* __restrict__ out, float* __restrict__ ws_m)
{
    __shared__ float wls[128];   // w_s
    __shared__ float qts[128];   // qterm
    const int b = blockIdx.y, c0 = blockIdx.x * 64;
    const int t = threadIdx.x;
    if (t < 32) *(f32x4*)&wls[t * 4] = *(const f32x4*)&W[256 + t * 4];
    else if (t < 64) *(f32x4*)&qts[(t - 32) * 4] = *(const f32x4*)&qterm[(size_t)b * Qn + (t - 32) * 4];
    __syncthreads();

    const int wave = t >> 6, lane = t & 63, g = lane >> 4, l15 = lane & 15;
    const int cw = wave * 16;
    const float* ctxB = ctx + (size_t)b * Cn * Dn;
    const _Float16* qhB = qh + (size_t)b * Qn * Dn;
    const _Float16* qTB = qT + (size_t)b * Dn * Qn;

    const int ccol = c0 + cw + l15;   // this lane's S^T column (ctx row)
    f32x4 acc1[8] = {};
#pragma unroll
    for (int kk = 0; kk < 4; ++kk) {
        const int dbase = kk * 32 + g * 8;
        const float* p = ctxB + (size_t)ccol * Dn + dbase;
        f32x4 v0 = *(const f32x4*)p, v1 = *(const f32x4*)(p + 4);
        f32x4 w0 = *(const f32x4*)&wls[dbase], w1 = *(const f32x4*)&wls[dbase + 4];
        float av[8] = {v0.x * w0.x, v0.y * w0.y, v0.z * w0.z, v0.w * w0.w,
                       v1.x * w1.x, v1.y * w1.y, v1.z * w1.z, v1.w * w1.w};
        half8 ah, al;
#pragma unroll
        for (int j = 0; j < 8; ++j) {
            _Float16 h = (_Float16)av[j];
            ah[j] = h;
            al[j] = (_Float16)(av[j] - (float)h);
        }
#pragma unroll
        for (int mt = 0; mt < 8; ++mt) {
            half8 qf = *(const half8*)(qhB + (size_t)(mt * 16 + l15) * Dn + dbase);
            acc1[mt] = __builtin_amdgcn_mfma_f32_16x16x32_f16(qf, ah, acc1[mt], 0, 0, 0);
            acc1[mt] = __builtin_amdgcn_mfma_f32_16x16x32_f16(qf, al, acc1[mt], 0, 0, 0);
        }
    }

    // add q_term (+mask); softmax over q per column
#pragma unroll
    for (int mt = 0; mt < 8; ++mt)
#pragma unroll
        for (int r = 0; r < 4; ++r) acc1[mt][r] += qts[mt * 16 + g * 4 + r];

    float mx = -3.4e38f;
#pragma unroll
    for (int mt = 0; mt < 8; ++mt)
#pragma unroll
        for (int r = 0; r < 4; ++r) mx = fmaxf(mx, acc1[mt][r]);
    mx = fmaxf(mx, __shfl_xor(mx, 16));
    mx = fmaxf(mx, __shfl_xor(mx, 32));
    float sum = 0.f;
#pragma unroll
    for (int mt = 0; mt < 8; ++mt)
#pragma unroll
        for (int r = 0; r < 4; ++r) {
            float pv = __expf(acc1[mt][r] - mx);
            acc1[mt][r] = pv;
            sum += pv;
        }
    sum += __shfl_xor(sum, 16);
    sum += __shfl_xor(sum, 32);
    if (g == 0) ws_m[(size_t)b * Cn + ccol] = mx + ct_g[(size_t)b * Cn + ccol];

    // pack P^T into A-frags (k-bijection k = g*4 + (j&3) + 16*(j>>2))
    half8 pa[4];
#pragma unroll
    for (int kk2 = 0; kk2 < 4; ++kk2)
#pragma unroll
        for (int j = 0; j < 8; ++j)
            pa[kk2][j] = (_Float16)acc1[2 * kk2 + (j >> 2)][j & 3];

    float inv[4];
#pragma unroll
    for (int r = 0; r < 4; ++r) inv[r] = 1.0f / __shfl(sum, g * 4 + r);

    // mm2: c2q[c][d] = sum_q P[c][q] * query[q][d]
    f32x4 acc2[8] = {};
#pragma unroll
    for (int kk2 = 0; kk2 < 4; ++kk2)
#pragma unroll
        for (int ntD = 0; ntD < 8; ++ntD) {
            const _Float16* bp = qTB + (size_t)(ntD * 16 + l15) * Qn + kk2 * 32 + g * 4;
            half4 r0 = *(const half4*)bp;
            half4 r1 = *(const half4*)(bp + 16);
            half8 qb;
            qb[0] = r0[0]; qb[1] = r0[1]; qb[2] = r0[2]; qb[3] = r0[3];
            qb[4] = r1[0]; qb[5] = r1[1]; qb[6] = r1[2]; qb[7] = r1[3];
            acc2[ntD] = __builtin_amdgcn_mfma_f32_16x16x32_f16(pa[kk2], qb, acc2[ntD], 0, 0, 0);
        }

    // epilogue: cols 1 (c2q) and 2 (ctx*c2q)
#pragma unroll
    for (int r = 0; r < 4; ++r) {
        int cl = cw + g * 4 + r;
        const float* crow = ctxB + (size_t)(c0 + cl) * Dn;
        float* orow = out + ((size_t)b * Cn + c0 + cl) * 512;
        float is = inv[r];
#pragma unroll
        for (int ntD = 0; ntD < 8; ++ntD) {
            int d = ntD * 16 + l15;
            float c2 = acc2[ntD][r] * is;
            float cv = crow[d];
            orow[128 + d] = c2;
            orow[256 + d] = cv * c2;
        }
    }
}

// ---------------- K2: softmax over c of m, partial q2c ----------------
__global__ __launch_bounds__(256) void k2_kernel(
    const float* __restrict__ ctx, const float* __restrict__ ws_m,
    float* __restrict__ ws_part)
{
    __shared__ float red[256];
    __shared__ float wv[128];
    __shared__ float partf[8 * 128];
    const int cg = blockIdx.x, b = blockIdx.y;
    const int t = threadIdx.x;
    const float* mrow = ws_m + (size_t)b * Cn;

    f32x4 v = *(const f32x4*)(mrow + t * 4);
    float mx = fmaxf(fmaxf(v.x, v.y), fmaxf(v.z, v.w));
    red[t] = mx;
    __syncthreads();
    for (int s = 128; s > 0; s >>= 1) {
        if (t < s) red[t] = fmaxf(red[t], red[t + s]);
        __syncthreads();
    }
    float M = red[0];
    __syncthreads();
    float sm = __expf(v.x - M) + __expf(v.y - M) + __expf(v.z - M) + __expf(v.w - M);
    red[t] = sm;
    __syncthreads();
    for (int s = 128; s > 0; s >>= 1) {
        if (t < s) red[t] += red[t + s];
        __syncthreads();
    }
    float invL = 1.0f / red[0];
    __syncthreads();

    if (t < 128) wv[t] = __expf(mrow[cg * 128 + t] - M) * invL;
    __syncthreads();

    const int d4 = (t & 31) * 4, grp = t >> 5;
    const float* cb = ctx + ((size_t)b * Cn + cg * 128 + grp * 16) * Dn;
    f32x4 a = {};
    for (int i = 0; i < 16; ++i) {
        f32x4 cv = *(const f32x4*)(cb + (size_t)i * Dn + d4);
        float w = wv[grp * 16 + i];
        a.x += w * cv.x; a.y += w * cv.y; a.z += w * cv.z; a.w += w * cv.w;
    }
    *(f32x4*)&partf[grp * 128 + d4] = a;
    __syncthreads();
    if (t < 128) {
        float s = 0.f;
#pragma unroll
        for (int grp2 = 0; grp2 < 8; ++grp2) s += partf[grp2 * 128 + t];
        ws_part[((size_t)b * 8 + cg) * 128 + t] = s;
    }
}

// ---------------- K3: reduce partials; cols 0 (ctx) and 3 (ctx*q2c) ----------------
__global__ __launch_bounds__(256) void k3_kernel(
    const float* __restrict__ ctx, const float* __restrict__ ws_part,
    float* __restrict__ out)
{
    __shared__ float q2c[128];
    const int ct = blockIdx.x, b = blockIdx.y;
    const int t = threadIdx.x;
    if (t < 128) {
        float s = 0.f;
#pragma unroll
        for (int cg = 0; cg < 8; ++cg)
            s += ws_part[((size_t)b * 8 + cg) * 128 + t];
        q2c[t] = s;
    }
    __syncthreads();
    const float* cb = ctx + ((size_t)b * Cn + ct * 128) * Dn;
    float* ob = out + ((size_t)b * Cn + ct * 128) * 512;
    for (int i4 = t; i4 < 128 * 32; i4 += 256) {
        int c = i4 >> 5, d4 = (i4 & 31) * 4;
        f32x4 v = *(const f32x4*)(cb + c * 128 + d4);
        f32x4 q = *(const f32x4*)(&q2c[d4]);
        *(f32x4*)(ob + (size_t)c * 512 + d4) = v;
        f32x4 w;
        w.x = v.x * q.x; w.y = v.y * q.y; w.z = v.z * q.z; w.w = v.w * q.w;
        *(f32x4*)(ob + (size_t)c * 512 + 384 + d4) = w;
    }
}

extern "C" void kernel_launch(void* const* d_in, const int* in_sizes, int n_in,
                              void* d_out, int out_size, void* d_ws, size_t ws_size,
                              hipStream_t stream) {
    const float* ctx  = (const float*)d_in[0];
    const float* qry  = (const float*)d_in[1];
    const float* W    = (const float*)d_in[2];
    const float* mask = (const float*)d_in[3];
    float* out = (float*)d_out;

    float* ws      = (float*)d_ws;
    float* ct_g    = ws;                       // 64K floats
    float* qterm   = ct_g + 65536;             // 8K
    float* ws_m    = qterm + 8192;             // 64K
    float* ws_part = ws_m + 65536;             // 64K
    _Float16* qh   = (_Float16*)(ws_part + 65536);   // 1M halves
    _Float16* qT   = qh + (size_t)Bn * Qn * Dn;      // 1M halves

    k0_kernel<<<dim3(9, Bn), 256, 0, stream>>>(ctx, qry, W, mask, ct_g, qterm, qh, qT);
    k1_kernel<<<dim3(16, Bn), 256, 0, stream>>>(ctx, qh, qT, W, qterm, ct_g, out, ws_m);
    k2_kernel<<<dim3(8, Bn), 256, 0, stream>>>(ctx, ws_m, ws_part);
    k3_kernel<<<dim3(8, Bn), 256, 0, stream>>>(ctx, ws_part, out);
}

// Round 3
// 55.713 us; speedup vs baseline: 1.9209x; 1.9209x over previous
//
#include <hip/hip_runtime.h>

#define NEGINF -1000000000.0f

typedef __attribute__((ext_vector_type(4))) float f32x4;
typedef _Float16 half8 __attribute__((ext_vector_type(8)));
typedef _Float16 half4 __attribute__((ext_vector_type(4)));

constexpr int Bn = 64, Cn = 1024, Qn = 128, Dn = 128;
constexpr int QSTR = 144;   // halves stride (288 B: 16B-aligned rows, even 8-way b128 banks)
constexpr int CSTR = 132;   // float stride for cq bounce (528 B, 16B-aligned)

// smem map (bytes):
//   0      qrow  128*144*2 = 36864      [later overlaid by cq 128*132*4 = 67584]
//   36864  qT2   36864                  [later overlaid by partf 4096, then cq]
//   73728  wfull 384 f   (1536)
//   75264  qts   128 f
//   75776  cts   128 f
//   76288  mloc  128 f
//   76800  wv    128 f
//   77312  red   16 f    (64)
// total 77376 -> 2 blocks/CU

__global__ __launch_bounds__(256) void k1_kernel(
    const float* __restrict__ ctx, const float* __restrict__ qry,
    const float* __restrict__ W, const float* __restrict__ mask,
    float* __restrict__ out, float* __restrict__ ws_part, float* __restrict__ ws_ms)
{
    __shared__ char smem[77376];
    _Float16* qrow = (_Float16*)smem;
    _Float16* qT2  = (_Float16*)(smem + 36864);
    float* wfull = (float*)(smem + 73728);
    float* qts   = (float*)(smem + 75264);
    float* cts   = (float*)(smem + 75776);
    float* mloc  = (float*)(smem + 76288);
    float* wv    = (float*)(smem + 76800);
    float* red   = (float*)(smem + 77312);
    float* partf = (float*)(smem + 36864);  // valid after mm2
    float* cq    = (float*)smem;            // valid after q2c pass

    const int b = blockIdx.y, cg = blockIdx.x, c0 = cg * 128;
    const int t = threadIdx.x;
    const float* ctxB = ctx + (size_t)b * Cn * Dn;
    const float* qryB = qry + (size_t)b * Qn * Dn;

    for (int i = t; i < 384; i += 256) wfull[i] = W[i];
    __syncthreads();

    // ---- stage query: fp16 row-major + bijection-transposed; q_term(+mask)
    {
        int q = t >> 1, h = t & 1;
        const float* qr = qryB + q * Dn + h * 64;
        int p = ((q >> 5) << 5) + 8 * ((q >> 2) & 3) + (q & 3) + 4 * ((q >> 4) & 1);
        float acc = 0.f;
        for (int j = 0; j < 64; j += 4) {
            f32x4 v = *(const f32x4*)(qr + j);
            int d = h * 64 + j;
            acc += v.x * wfull[128 + d] + v.y * wfull[128 + d + 1]
                 + v.z * wfull[128 + d + 2] + v.w * wfull[128 + d + 3];
            half4 hv;
            hv[0] = (_Float16)v.x; hv[1] = (_Float16)v.y;
            hv[2] = (_Float16)v.z; hv[3] = (_Float16)v.w;
            *(half4*)&qrow[q * QSTR + d] = hv;
            qT2[(d + 0) * QSTR + p] = hv[0];
            qT2[(d + 1) * QSTR + p] = hv[1];
            qT2[(d + 2) * QSTR + p] = hv[2];
            qT2[(d + 3) * QSTR + p] = hv[3];
        }
        acc += __shfl_xor(acc, 1);
        if (h == 0) qts[q] = acc + (1.0f - mask[b * Qn + q]) * NEGINF;
    }
    // ---- c_term for this ctile (also warms L1 with ctx rows)
    {
        int c = t >> 1, h = t & 1;
        const float* cr = ctxB + (size_t)(c0 + c) * Dn + h * 64;
        float acc = 0.f;
        for (int j = 0; j < 64; j += 4) {
            f32x4 v = *(const f32x4*)(cr + j);
            int d = h * 64 + j;
            acc += v.x * wfull[d] + v.y * wfull[d + 1] + v.z * wfull[d + 2] + v.w * wfull[d + 3];
        }
        acc += __shfl_xor(acc, 1);
        if (h == 0) cts[c] = acc;
    }
    __syncthreads();

    const int wave = t >> 6, lane = t & 63, g = lane >> 4, l15 = lane & 15;
    const int cw = wave * 32;

    // ---- mm1: S^T[q][c], A=query rows (LDS fp16), B=ctx*w_s (global, fp16 hi/lo)
    f32x4 acc1[8][2] = {};
#pragma unroll
    for (int kk = 0; kk < 4; ++kk) {
        const int dbase = kk * 32 + g * 8;
        f32x4 w0 = *(const f32x4*)&wfull[256 + dbase];
        f32x4 w1 = *(const f32x4*)&wfull[256 + dbase + 4];
        half8 ah[2], al[2];
#pragma unroll
        for (int nt = 0; nt < 2; ++nt) {
            const float* p = ctxB + (size_t)(c0 + cw + nt * 16 + l15) * Dn + dbase;
            f32x4 v0 = *(const f32x4*)p, v1 = *(const f32x4*)(p + 4);
            float av[8] = {v0.x * w0.x, v0.y * w0.y, v0.z * w0.z, v0.w * w0.w,
                           v1.x * w1.x, v1.y * w1.y, v1.z * w1.z, v1.w * w1.w};
#pragma unroll
            for (int j = 0; j < 8; ++j) {
                _Float16 hh = (_Float16)av[j];
                ah[nt][j] = hh;
                al[nt][j] = (_Float16)(av[j] - (float)hh);
            }
        }
#pragma unroll
        for (int mt = 0; mt < 8; ++mt) {
            half8 qf = *(const half8*)&qrow[(mt * 16 + l15) * QSTR + dbase];
#pragma unroll
            for (int nt = 0; nt < 2; ++nt) {
                acc1[mt][nt] = __builtin_amdgcn_mfma_f32_16x16x32_f16(qf, ah[nt], acc1[mt][nt], 0, 0, 0);
                acc1[mt][nt] = __builtin_amdgcn_mfma_f32_16x16x32_f16(qf, al[nt], acc1[mt][nt], 0, 0, 0);
            }
        }
    }

    // ---- +q_term(+mask); softmax over q per column; mloc = colmax + c_term
#pragma unroll
    for (int mt = 0; mt < 8; ++mt)
#pragma unroll
        for (int r = 0; r < 4; ++r) {
            float qv = qts[mt * 16 + g * 4 + r];
            acc1[mt][0][r] += qv;
            acc1[mt][1][r] += qv;
        }

    float psum[2];
#pragma unroll
    for (int nt = 0; nt < 2; ++nt) {
        float mx = -3.4e38f;
#pragma unroll
        for (int mt = 0; mt < 8; ++mt)
#pragma unroll
            for (int r = 0; r < 4; ++r) mx = fmaxf(mx, acc1[mt][nt][r]);
        mx = fmaxf(mx, __shfl_xor(mx, 16));
        mx = fmaxf(mx, __shfl_xor(mx, 32));
        float sum = 0.f;
#pragma unroll
        for (int mt = 0; mt < 8; ++mt)
#pragma unroll
            for (int r = 0; r < 4; ++r) {
                float pv = __expf(acc1[mt][nt][r] - mx);
                acc1[mt][nt][r] = pv;
                sum += pv;
            }
        sum += __shfl_xor(sum, 16);
        sum += __shfl_xor(sum, 32);
        psum[nt] = sum;
        int cl = cw + nt * 16 + l15;
        if (g == 0) mloc[cl] = mx + cts[cl];
    }

    // ---- pack P^T into A-frags (bijection k = 4g+(j&3)+16(j>>2)) + inv sums
    half8 pa[4][2];
#pragma unroll
    for (int kk2 = 0; kk2 < 4; ++kk2)
#pragma unroll
        for (int nt = 0; nt < 2; ++nt)
#pragma unroll
            for (int j = 0; j < 8; ++j)
                pa[kk2][nt][j] = (_Float16)acc1[2 * kk2 + (j >> 2)][nt][j & 3];

    float inv[2][4];
#pragma unroll
    for (int nt = 0; nt < 2; ++nt)
#pragma unroll
        for (int r = 0; r < 4; ++r)
            inv[nt][r] = 1.0f / __shfl(psum[nt], g * 4 + r);

    // ---- mm2: c2q^T-block — B-frag is ONE b128 from bijection-layout qT2
    f32x4 acc2[2][8] = {};
#pragma unroll
    for (int kk2 = 0; kk2 < 4; ++kk2)
#pragma unroll
        for (int ntD = 0; ntD < 8; ++ntD) {
            half8 qb = *(const half8*)&qT2[(ntD * 16 + l15) * QSTR + kk2 * 32 + 8 * g];
#pragma unroll
            for (int nt1 = 0; nt1 < 2; ++nt1)
                acc2[nt1][ntD] = __builtin_amdgcn_mfma_f32_16x16x32_f16(pa[kk2][nt1], qb, acc2[nt1][ntD], 0, 0, 0);
        }
    __syncthreads();   // qT2 dead; all mloc written

    // ---- q2c partials: Mloc, wv = exp(m-Mloc), Sloc, partial = sum wv*ctx
    float Mloc;
    {
        float v = (t < 128) ? mloc[t] : -3.4e38f;
        float m = v;
#pragma unroll
        for (int off = 1; off < 64; off <<= 1) m = fmaxf(m, __shfl_xor(m, off));
        if (lane == 0) red[wave] = m;
        __syncthreads();
        Mloc = fmaxf(fmaxf(red[0], red[1]), fmaxf(red[2], red[3]));
        float e = (t < 128) ? __expf(v - Mloc) : 0.f;
        if (t < 128) wv[t] = e;
        float s = e;
#pragma unroll
        for (int off = 1; off < 64; off <<= 1) s += __shfl_xor(s, off);
        if (lane == 0) red[4 + wave] = s;
        __syncthreads();
    }
    float Sloc = red[4] + red[5] + red[6] + red[7];
    {
        int grp = t >> 5, d4 = (t & 31) * 4;
        const float* cb = ctxB + (size_t)(c0 + grp * 16) * Dn;
        f32x4 a = {};
        for (int i = 0; i < 16; ++i) {
            f32x4 cv = *(const f32x4*)(cb + (size_t)i * Dn + d4);
            float w = wv[grp * 16 + i];
            a.x += w * cv.x; a.y += w * cv.y; a.z += w * cv.z; a.w += w * cv.w;
        }
        *(f32x4*)&partf[grp * 128 + d4] = a;
        __syncthreads();
        if (t < 128) {
            float s = 0.f;
#pragma unroll
            for (int g2 = 0; g2 < 8; ++g2) s += partf[g2 * 128 + t];
            ws_part[((size_t)(b * 8 + cg)) * 128 + t] = s;
        }
        if (t == 0) {
            ws_ms[(b * 8 + cg) * 2 + 0] = Mloc;
            ws_ms[(b * 8 + cg) * 2 + 1] = Sloc;
        }
    }
    __syncthreads();   // partf dead -> cq may overlay

    // ---- bounce c2q through LDS, coalesced store of cols 1,2
#pragma unroll
    for (int nt1 = 0; nt1 < 2; ++nt1)
#pragma unroll
        for (int r = 0; r < 4; ++r) {
            int c = cw + nt1 * 16 + g * 4 + r;
            float is = inv[nt1][r];
#pragma unroll
            for (int ntD = 0; ntD < 8; ++ntD)
                cq[c * CSTR + ntD * 16 + l15] = acc2[nt1][ntD][r] * is;
        }
    __syncthreads();
    for (int step = 0; step < 16; ++step) {
        int c = (t >> 5) + step * 8, d4 = (t & 31) * 4;
        f32x4 q = *(const f32x4*)&cq[c * CSTR + d4];
        f32x4 cv = *(const f32x4*)(ctxB + (size_t)(c0 + c) * Dn + d4);
        float* orow = out + ((size_t)(b * Cn + c0 + c)) * 512;
        *(f32x4*)(orow + 128 + d4) = q;
        f32x4 pr;
        pr.x = cv.x * q.x; pr.y = cv.y * q.y; pr.z = cv.z * q.z; pr.w = cv.w * q.w;
        *(f32x4*)(orow + 256 + d4) = pr;
    }
}

// ---- K3: combine 8 chunk-partials -> q2c; write cols 0 (ctx) and 3 (ctx*q2c)
__global__ __launch_bounds__(256) void k3_kernel(
    const float* __restrict__ ctx, const float* __restrict__ ws_part,
    const float* __restrict__ ws_ms, float* __restrict__ out)
{
    __shared__ float q2cs[128];
    const int ct = blockIdx.x, b = blockIdx.y, t = threadIdx.x;
    if (t < 128) {
        const float* ms = ws_ms + b * 16;
        float Mg = -3.4e38f;
#pragma unroll
        for (int i = 0; i < 8; ++i) Mg = fmaxf(Mg, ms[2 * i]);
        float num = 0.f, den = 0.f;
#pragma unroll
        for (int i = 0; i < 8; ++i) {
            float e = __expf(ms[2 * i] - Mg);
            num += e * ws_part[((size_t)(b * 8 + i)) * 128 + t];
            den += e * ms[2 * i + 1];
        }
        q2cs[t] = num / den;
    }
    __syncthreads();
    const float* cb = ctx + ((size_t)b * Cn + ct * 128) * Dn;
    float* ob = out + ((size_t)(b * Cn) + ct * 128) * 512;
    for (int step = 0; step < 16; ++step) {
        int c = (t >> 5) + step * 8, d4 = (t & 31) * 4;
        f32x4 v = *(const f32x4*)(cb + (size_t)c * Dn + d4);
        f32x4 q = *(const f32x4*)&q2cs[d4];
        *(f32x4*)(ob + (size_t)c * 512 + d4) = v;
        f32x4 w;
        w.x = v.x * q.x; w.y = v.y * q.y; w.z = v.z * q.z; w.w = v.w * q.w;
        *(f32x4*)(ob + (size_t)c * 512 + 384 + d4) = w;
    }
}

extern "C" void kernel_launch(void* const* d_in, const int* in_sizes, int n_in,
                              void* d_out, int out_size, void* d_ws, size_t ws_size,
                              hipStream_t stream) {
    const float* ctx  = (const float*)d_in[0];
    const float* qry  = (const float*)d_in[1];
    const float* W    = (const float*)d_in[2];
    const float* mask = (const float*)d_in[3];
    float* out = (float*)d_out;

    float* ws_part = (float*)d_ws;                    // 64*8*128 f32 = 256 KB
    float* ws_ms   = ws_part + (size_t)Bn * 8 * 128;  // 64*8*2 f32 = 4 KB

    k1_kernel<<<dim3(8, Bn), 256, 0, stream>>>(ctx, qry, W, mask, out, ws_part, ws_ms);
    k3_kernel<<<dim3(8, Bn), 256, 0, stream>>>(ctx, ws_part, ws_ms, out);
}